// Round 8
// baseline (72.144 us; speedup 1.0000x reference)
//
#include <hip/hip_runtime.h>

#define HALO 3
#define SUB_H 8         /* rows per wave */
#define WAVES_Y 2       /* waves per block (independent y-subtiles) */
#define STRIP_OUT 240   /* output columns per wave; input strip = 256 cols */
#define EPS 0.002f
#define RING 10         /* register ring of raw rows (7 window + 3 prefetch) */

typedef float f32x4 __attribute__((ext_vector_type(4)));

__device__ __forceinline__ float rcp_fast(float x) { return __builtin_amdgcn_rcpf(x); }

// Whole-wave lane shifts at VALU speed (no LDS pipe, no lgkm waits).
// 0x138 = wf_sr1: lane i <- lane i-1 (lane 0 <- 0 via bound_ctrl)  == shfl_up(1)
// 0x130 = wf_sl1: lane i <- lane i+1 (lane 63 <- 0)                == shfl_down(1)
__device__ __forceinline__ float dpp_up1(float x) {
    return __int_as_float(__builtin_amdgcn_update_dpp(0, __float_as_int(x), 0x138, 0xf, 0xf, true));
}
__device__ __forceinline__ float dpp_dn1(float x) {
    return __int_as_float(__builtin_amdgcn_update_dpp(0, __float_as_int(x), 0x130, 0xf, 0xf, true));
}

// 2 independent waves per block, each owning an 8-row x 240-col output tile.
// Raw input rows live in a 10-deep register ring (loop fully unrolled, all
// indices compile-time): vertical sliding-window sub comes from registers
// (no re-load), add-rows are prefetched 3 iterations ahead directly into
// their ring slot. Horizontal 7-sums via DPP wave shifts. No LDS, no barriers.
__global__ __launch_bounds__(64 * WAVES_Y) void ProgressiveTransfer_kernel(
    const float* __restrict__ G, const float* __restrict__ S,
    float* __restrict__ out, int H, int W)
{
    const int t  = threadIdx.x;                        // lane 0..63
    const int wv = threadIdx.y;
    const int ch = blockIdx.z;
    const int y0 = (blockIdx.y * WAVES_Y + wv) * SUB_H;
    const int col0 = blockIdx.x * STRIP_OUT - 8 + 4 * t;
    const bool cin = (col0 >= 0) && (col0 + 3 < W);    // float4 all-in or all-out

    const size_t plane = (size_t)H * W;
    const float* Gp = G + (size_t)ch * plane;
    const float* Sp = S + (size_t)ch * plane;

    auto ld = [&](const float* __restrict__ P, int r) -> f32x4 {
        if (cin && r >= 0 && r < H)
            return *reinterpret_cast<const f32x4*>(P + (size_t)r * W + col0);
        return (f32x4){0.f, 0.f, 0.f, 0.f};
    };

    // Ring slot for image row r is (r - y0 + 3) mod RING.
    f32x4 rg[RING], rs[RING];

    // Vertical window sums over rows [y-3, y+3] for the lane's 4 columns.
    float g1[4] = {0,0,0,0}, g2[4] = {0,0,0,0};
    float s1[4] = {0,0,0,0}, s2[4] = {0,0,0,0};

    // Prologue: rows y0-3..y0+2 -> slots 0..5 (init), y0+3..y0+5 -> slots 6..8
    // (prefetch for iters 0..2). 18 loads issued back-to-back (max MLP).
#pragma unroll
    for (int k = 0; k < 9; ++k) rg[k] = ld(Gp, y0 - HALO + k);
#pragma unroll
    for (int k = 0; k < 9; ++k) rs[k] = ld(Sp, y0 - HALO + k);
#pragma unroll
    for (int k = 0; k < 6; ++k) {
#pragma unroll
        for (int j = 0; j < 4; ++j) {
            g1[j] += rg[k][j]; g2[j] = fmaf(rg[k][j], rg[k][j], g2[j]);
            s1[j] += rs[k][j]; s2[j] = fmaf(rs[k][j], rs[k][j], s2[j]);
        }
    }

    // Per-column horizontal clipped counts (loop-invariant).
    float cntx[4];
#pragma unroll
    for (int j = 0; j < 4; ++j) {
        const int x = col0 + j;
        cntx[j] = (float)(min(x + HALO, W - 1) - max(x - HALO, 0) + 1);
    }

    const bool wout = (t >= 2) && (t < 62) && (col0 < W);

#pragma unroll
    for (int i = 0; i < SUB_H; ++i) {
        const int y = y0 + i;

        // Drop row y-4 from the ring (slot holds zeros when y-4 < 0).
        if (i >= 1) {
            const int sl = (i - 1) % RING;
#pragma unroll
            for (int j = 0; j < 4; ++j) {
                g1[j] -= rg[sl][j]; g2[j] = fmaf(-rg[sl][j], rg[sl][j], g2[j]);
                s1[j] -= rs[sl][j]; s2[j] = fmaf(-rs[sl][j], rs[sl][j], s2[j]);
            }
        }
        // Gain row y+3 (loaded 3 iterations ago).
        {
            const int al = (i + 6) % RING;
#pragma unroll
            for (int j = 0; j < 4; ++j) {
                g1[j] += rg[al][j]; g2[j] = fmaf(rg[al][j], rg[al][j], g2[j]);
                s1[j] += rs[al][j]; s2[j] = fmaf(rs[al][j], rs[al][j], s2[j]);
            }
        }
        // Prefetch add-row of iteration i+3 (row y+6) into its slot.
        // (Slot (i+9)%RING was sub-read above in this same iteration.)
        if (i + 3 < SUB_H) {
            const int pl = (i + 9) % RING;
            rg[pl] = ld(Gp, y + 6);
            rs[pl] = ld(Sp, y + 6);
        }

        // Horizontal 7-sums via DPP wave shifts (pure VALU).
        float hg1[4], hg2[4], hs1[4], hs2[4];
        auto hsum = [&](const float* c, float* o) {
            const float t1 = c[0] + c[1], t2 = c[2] + c[3];
            const float S4 = t1 + t2;
            const float sfx3 = c[1] + t2;     // c1+c2+c3
            const float pfx3 = t1 + c[2];     // c0+c1+c2
            const float S1m = dpp_up1(c[3]);
            const float S2m = dpp_up1(t2);
            const float S3m = dpp_up1(sfx3);
            const float P1p = dpp_dn1(c[0]);
            const float P2p = dpp_dn1(t1);
            const float P3p = dpp_dn1(pfx3);
            o[0] = S3m + S4;
            o[1] = S2m + S4 + P1p;
            o[2] = S1m + S4 + P2p;
            o[3] = S4 + P3p;
        };
        hsum(g1, hg1); hsum(g2, hg2); hsum(s1, hs1); hsum(s2, hs2);

        const float cnty = (float)(min(y + HALO, H - 1) - max(y - HALO, 0) + 1);

        f32x4 av, bv;
#pragma unroll
        for (int j = 0; j < 4; ++j) {
            const float cnt  = cntx[j] * cnty;
            const float inv  = rcp_fast(cnt);
            const float invm = rcp_fast(cnt - 1.0f);
            const float mg = hg1[j] * inv;
            const float ms = hs1[j] * inv;
            const float varg = (hg2[j] - hg1[j] * mg) * invm;
            const float vars = (hs2[j] - hs1[j] * ms) * invm;
            const float stdg = __builtin_amdgcn_sqrtf(fmaxf(varg, 0.0f));
            const float stds = __builtin_amdgcn_sqrtf(fmaxf(vars, 0.0f));
            const float alpha = stdg * rcp_fast(stds + EPS);
            av[j] = alpha;
            bv[j] = mg - alpha * ms;
        }

        if (wout) {
            const size_t base = (size_t)ch * plane + (size_t)y * W + col0;
            __builtin_nontemporal_store(av, reinterpret_cast<f32x4*>(out + base));
            __builtin_nontemporal_store(bv, reinterpret_cast<f32x4*>(out + 3 * plane + base));
        }
    }
}

extern "C" void kernel_launch(void* const* d_in, const int* in_sizes, int n_in,
                              void* d_out, int out_size, void* d_ws, size_t ws_size,
                              hipStream_t stream) {
    (void)n_in; (void)d_ws; (void)ws_size; (void)in_sizes; (void)out_size;
    const float* guidance = (const float*)d_in[0];
    const float* source   = (const float*)d_in[1];
    float* out = (float*)d_out;

    const int C = 3, H = 2048, W = 3072;
    const int nstrips = (W + STRIP_OUT - 1) / STRIP_OUT;   // 13

    dim3 block(64, WAVES_Y, 1);
    dim3 grid(nstrips, H / (WAVES_Y * SUB_H), C);          // 13 x 128 x 3
    ProgressiveTransfer_kernel<<<grid, block, 0, stream>>>(guidance, source, out, H, W);
}

// Round 9
// 62.239 us; speedup vs baseline: 1.1592x; 1.1592x over previous
//
#include <hip/hip_runtime.h>

#define HALO 3
#define SUB_H 16        /* rows per wave */
#define WAVES_Y 2       /* waves per block (independent y-subtiles) */
#define STRIP_OUT 240   /* output columns per wave; input strip = 256 cols */
#define EPS 0.002f
#define RING 10         /* register ring of raw rows (7 window + 3 prefetch) */

#define NSTRIPS 13
#define NYT 64          /* y-tiles (of WAVES_Y*SUB_H=32 rows) */
#define NCH 3
#define NWG (NSTRIPS * NYT * NCH)   /* 2496 */
#define NXCD 8
#define QXCD (NWG / NXCD)           /* 312, NWG%8==0 -> bijective */

typedef float f32x4 __attribute__((ext_vector_type(4)));

__device__ __forceinline__ float rcp_fast(float x) { return __builtin_amdgcn_rcpf(x); }

// Whole-wave lane shifts at VALU speed (no LDS pipe, no lgkm waits).
// 0x138 = wf_sr1: lane i <- lane i-1 (lane 0 <- 0 via bound_ctrl)  == shfl_up(1)
// 0x130 = wf_sl1: lane i <- lane i+1 (lane 63 <- 0)                == shfl_down(1)
__device__ __forceinline__ float dpp_up1(float x) {
    return __int_as_float(__builtin_amdgcn_update_dpp(0, __float_as_int(x), 0x138, 0xf, 0xf, true));
}
__device__ __forceinline__ float dpp_dn1(float x) {
    return __int_as_float(__builtin_amdgcn_update_dpp(0, __float_as_int(x), 0x130, 0xf, 0xf, true));
}

// 2 independent waves per block, each owning a 16-row x 240-col output tile.
// Raw input rows in a 10-deep register ring (fully unrolled -> compile-time
// indices); add-rows prefetched 3 iterations ahead; horizontal 7-sums via DPP
// wave shifts. No LDS, no barriers. NT stores.
// XCD swizzle: work is assigned column-major so vertically-adjacent tiles
// (which share 6 halo rows) co-reside on one XCD's L2.
__global__ __launch_bounds__(64 * WAVES_Y) void ProgressiveTransfer_kernel(
    const float* __restrict__ G, const float* __restrict__ S,
    float* __restrict__ out, int H, int W)
{
    const int t  = threadIdx.x;                        // lane 0..63
    const int wv = threadIdx.y;

    // ---- bijective XCD swizzle (m204; NWG % 8 == 0 so q-form suffices) ----
    const int orig = blockIdx.x + NSTRIPS * (blockIdx.y + NYT * blockIdx.z);
    const int wg   = (orig % NXCD) * QXCD + orig / NXCD;
    // column-major decode: consecutive wg walk DOWN a strip column
    const int ch  = wg / (NSTRIPS * NYT);
    const int rem = wg - ch * (NSTRIPS * NYT);
    const int sx  = rem / NYT;                         // strip index 0..12
    const int sy  = rem % NYT;                         // y-tile index 0..63

    const int y0 = (sy * WAVES_Y + wv) * SUB_H;
    const int col0 = sx * STRIP_OUT - 8 + 4 * t;
    const bool cin = (col0 >= 0) && (col0 + 3 < W);    // float4 all-in or all-out

    const size_t plane = (size_t)H * W;
    const float* Gp = G + (size_t)ch * plane;
    const float* Sp = S + (size_t)ch * plane;

    auto ld = [&](const float* __restrict__ P, int r) -> f32x4 {
        if (cin && r >= 0 && r < H)
            return *reinterpret_cast<const f32x4*>(P + (size_t)r * W + col0);
        return (f32x4){0.f, 0.f, 0.f, 0.f};
    };

    // Ring slot for image row r is (r - y0 + 3) mod RING.
    f32x4 rg[RING], rs[RING];

    // Vertical window sums over rows [y-3, y+3] for the lane's 4 columns.
    float g1[4] = {0,0,0,0}, g2[4] = {0,0,0,0};
    float s1[4] = {0,0,0,0}, s2[4] = {0,0,0,0};

    // Prologue: rows y0-3..y0+2 -> slots 0..5 (init), y0+3..y0+5 -> slots 6..8
    // (prefetch for iters 0..2). 18 loads issued back-to-back (max MLP).
#pragma unroll
    for (int k = 0; k < 9; ++k) rg[k] = ld(Gp, y0 - HALO + k);
#pragma unroll
    for (int k = 0; k < 9; ++k) rs[k] = ld(Sp, y0 - HALO + k);
#pragma unroll
    for (int k = 0; k < 6; ++k) {
#pragma unroll
        for (int j = 0; j < 4; ++j) {
            g1[j] += rg[k][j]; g2[j] = fmaf(rg[k][j], rg[k][j], g2[j]);
            s1[j] += rs[k][j]; s2[j] = fmaf(rs[k][j], rs[k][j], s2[j]);
        }
    }

    // Per-column horizontal clipped counts (loop-invariant).
    float cntx[4];
#pragma unroll
    for (int j = 0; j < 4; ++j) {
        const int x = col0 + j;
        cntx[j] = (float)(min(x + HALO, W - 1) - max(x - HALO, 0) + 1);
    }

    const bool wout = (t >= 2) && (t < 62) && (col0 < W);

#pragma unroll
    for (int i = 0; i < SUB_H; ++i) {
        const int y = y0 + i;

        // Drop row y-4 from the ring (slot holds zeros when y-4 < 0).
        if (i >= 1) {
            const int sl = (i - 1) % RING;
#pragma unroll
            for (int j = 0; j < 4; ++j) {
                g1[j] -= rg[sl][j]; g2[j] = fmaf(-rg[sl][j], rg[sl][j], g2[j]);
                s1[j] -= rs[sl][j]; s2[j] = fmaf(-rs[sl][j], rs[sl][j], s2[j]);
            }
        }
        // Gain row y+3 (loaded 3 iterations ago).
        {
            const int al = (i + 6) % RING;
#pragma unroll
            for (int j = 0; j < 4; ++j) {
                g1[j] += rg[al][j]; g2[j] = fmaf(rg[al][j], rg[al][j], g2[j]);
                s1[j] += rs[al][j]; s2[j] = fmaf(rs[al][j], rs[al][j], s2[j]);
            }
        }
        // Prefetch add-row of iteration i+3 (row y+6) into its slot.
        // (Slot (i+9)%RING was sub-read above in this same iteration.)
        if (i + 3 < SUB_H) {
            const int pl = (i + 9) % RING;
            rg[pl] = ld(Gp, y + 6);
            rs[pl] = ld(Sp, y + 6);
        }

        // Horizontal 7-sums via DPP wave shifts (pure VALU).
        float hg1[4], hg2[4], hs1[4], hs2[4];
        auto hsum = [&](const float* c, float* o) {
            const float t1 = c[0] + c[1], t2 = c[2] + c[3];
            const float S4 = t1 + t2;
            const float sfx3 = c[1] + t2;     // c1+c2+c3
            const float pfx3 = t1 + c[2];     // c0+c1+c2
            const float S1m = dpp_up1(c[3]);
            const float S2m = dpp_up1(t2);
            const float S3m = dpp_up1(sfx3);
            const float P1p = dpp_dn1(c[0]);
            const float P2p = dpp_dn1(t1);
            const float P3p = dpp_dn1(pfx3);
            o[0] = S3m + S4;
            o[1] = S2m + S4 + P1p;
            o[2] = S1m + S4 + P2p;
            o[3] = S4 + P3p;
        };
        hsum(g1, hg1); hsum(g2, hg2); hsum(s1, hs1); hsum(s2, hs2);

        const float cnty = (float)(min(y + HALO, H - 1) - max(y - HALO, 0) + 1);

        f32x4 av, bv;
#pragma unroll
        for (int j = 0; j < 4; ++j) {
            const float cnt  = cntx[j] * cnty;
            const float inv  = rcp_fast(cnt);
            const float invm = rcp_fast(cnt - 1.0f);
            const float mg = hg1[j] * inv;
            const float ms = hs1[j] * inv;
            const float varg = (hg2[j] - hg1[j] * mg) * invm;
            const float vars = (hs2[j] - hs1[j] * ms) * invm;
            const float stdg = __builtin_amdgcn_sqrtf(fmaxf(varg, 0.0f));
            const float stds = __builtin_amdgcn_sqrtf(fmaxf(vars, 0.0f));
            const float alpha = stdg * rcp_fast(stds + EPS);
            av[j] = alpha;
            bv[j] = mg - alpha * ms;
        }

        if (wout) {
            const size_t base = (size_t)ch * plane + (size_t)y * W + col0;
            __builtin_nontemporal_store(av, reinterpret_cast<f32x4*>(out + base));
            __builtin_nontemporal_store(bv, reinterpret_cast<f32x4*>(out + 3 * plane + base));
        }
    }
}

extern "C" void kernel_launch(void* const* d_in, const int* in_sizes, int n_in,
                              void* d_out, int out_size, void* d_ws, size_t ws_size,
                              hipStream_t stream) {
    (void)n_in; (void)d_ws; (void)ws_size; (void)in_sizes; (void)out_size;
    const float* guidance = (const float*)d_in[0];
    const float* source   = (const float*)d_in[1];
    float* out = (float*)d_out;

    const int H = 2048, W = 3072;

    dim3 block(64, WAVES_Y, 1);
    dim3 grid(NSTRIPS, NYT, NCH);                      // 13 x 64 x 3 = 2496
    ProgressiveTransfer_kernel<<<grid, block, 0, stream>>>(guidance, source, out, H, W);
}

// Round 10
// 58.808 us; speedup vs baseline: 1.2268x; 1.0583x over previous
//
#include <hip/hip_runtime.h>

#define HALO 3
#define SUB_H 32        /* rows per wave */
#define WAVES_Y 2       /* waves per block (independent y-subtiles) */
#define STRIP_OUT 240   /* output columns per wave; input strip = 256 cols */
#define EPS 0.002f
#define RING 10         /* register ring of raw rows (7 window + 3 prefetch) */

#define NSTRIPS 13
#define NYT 32          /* y-tiles (of WAVES_Y*SUB_H=64 rows) */
#define NCH 3
#define NWG (NSTRIPS * NYT * NCH)   /* 1248 */
#define NXCD 8
#define QXCD (NWG / NXCD)           /* 156, NWG%8==0 -> bijective */

typedef float f32x4 __attribute__((ext_vector_type(4)));

__device__ __forceinline__ float rcp_fast(float x) { return __builtin_amdgcn_rcpf(x); }

// Whole-wave lane shifts at VALU speed (no LDS pipe, no lgkm waits).
// 0x138 = wf_sr1: lane i <- lane i-1 (lane 0 <- 0 via bound_ctrl)  == shfl_up(1)
// 0x130 = wf_sl1: lane i <- lane i+1 (lane 63 <- 0)                == shfl_down(1)
__device__ __forceinline__ float dpp_up1(float x) {
    return __int_as_float(__builtin_amdgcn_update_dpp(0, __float_as_int(x), 0x138, 0xf, 0xf, true));
}
__device__ __forceinline__ float dpp_dn1(float x) {
    return __int_as_float(__builtin_amdgcn_update_dpp(0, __float_as_int(x), 0x130, 0xf, 0xf, true));
}

// 2 independent waves per block, each owning a 32-row x 240-col output tile.
// Raw input rows in a 10-deep register ring (fully unrolled -> compile-time
// indices); add-rows prefetched 3 iterations ahead; horizontal 7-sums via DPP
// wave shifts. No LDS, no barriers. NT stores.
// XCD swizzle: work is assigned column-major so vertically-adjacent tiles
// (which share 6 halo rows) co-reside on one XCD's L2.
__global__ __launch_bounds__(64 * WAVES_Y) void ProgressiveTransfer_kernel(
    const float* __restrict__ G, const float* __restrict__ S,
    float* __restrict__ out, int H, int W)
{
    const int t  = threadIdx.x;                        // lane 0..63
    const int wv = threadIdx.y;

    // ---- bijective XCD swizzle (m204; NWG % 8 == 0 so q-form suffices) ----
    const int orig = blockIdx.x + NSTRIPS * (blockIdx.y + NYT * blockIdx.z);
    const int wg   = (orig % NXCD) * QXCD + orig / NXCD;
    // column-major decode: consecutive wg walk DOWN a strip column
    const int ch  = wg / (NSTRIPS * NYT);
    const int rem = wg - ch * (NSTRIPS * NYT);
    const int sx  = rem / NYT;                         // strip index 0..12
    const int sy  = rem % NYT;                         // y-tile index 0..31

    const int y0 = (sy * WAVES_Y + wv) * SUB_H;
    const int col0 = sx * STRIP_OUT - 8 + 4 * t;
    const bool cin = (col0 >= 0) && (col0 + 3 < W);    // float4 all-in or all-out

    const size_t plane = (size_t)H * W;
    const float* Gp = G + (size_t)ch * plane;
    const float* Sp = S + (size_t)ch * plane;

    auto ld = [&](const float* __restrict__ P, int r) -> f32x4 {
        if (cin && r >= 0 && r < H)
            return *reinterpret_cast<const f32x4*>(P + (size_t)r * W + col0);
        return (f32x4){0.f, 0.f, 0.f, 0.f};
    };

    // Ring slot for image row r is (r - y0 + 3) mod RING.
    f32x4 rg[RING], rs[RING];

    // Vertical window sums over rows [y-3, y+3] for the lane's 4 columns.
    float g1[4] = {0,0,0,0}, g2[4] = {0,0,0,0};
    float s1[4] = {0,0,0,0}, s2[4] = {0,0,0,0};

    // Prologue: rows y0-3..y0+2 -> slots 0..5 (init), y0+3..y0+5 -> slots 6..8
    // (prefetch for iters 0..2). 18 loads issued back-to-back (max MLP).
#pragma unroll
    for (int k = 0; k < 9; ++k) rg[k] = ld(Gp, y0 - HALO + k);
#pragma unroll
    for (int k = 0; k < 9; ++k) rs[k] = ld(Sp, y0 - HALO + k);
#pragma unroll
    for (int k = 0; k < 6; ++k) {
#pragma unroll
        for (int j = 0; j < 4; ++j) {
            g1[j] += rg[k][j]; g2[j] = fmaf(rg[k][j], rg[k][j], g2[j]);
            s1[j] += rs[k][j]; s2[j] = fmaf(rs[k][j], rs[k][j], s2[j]);
        }
    }

    // Per-column horizontal clipped counts (loop-invariant).
    float cntx[4];
#pragma unroll
    for (int j = 0; j < 4; ++j) {
        const int x = col0 + j;
        cntx[j] = (float)(min(x + HALO, W - 1) - max(x - HALO, 0) + 1);
    }

    const bool wout = (t >= 2) && (t < 62) && (col0 < W);

#pragma unroll
    for (int i = 0; i < SUB_H; ++i) {
        const int y = y0 + i;

        // Drop row y-4 from the ring (slot holds zeros when y-4 < 0).
        if (i >= 1) {
            const int sl = (i - 1) % RING;
#pragma unroll
            for (int j = 0; j < 4; ++j) {
                g1[j] -= rg[sl][j]; g2[j] = fmaf(-rg[sl][j], rg[sl][j], g2[j]);
                s1[j] -= rs[sl][j]; s2[j] = fmaf(-rs[sl][j], rs[sl][j], s2[j]);
            }
        }
        // Gain row y+3 (loaded 3 iterations ago).
        {
            const int al = (i + 6) % RING;
#pragma unroll
            for (int j = 0; j < 4; ++j) {
                g1[j] += rg[al][j]; g2[j] = fmaf(rg[al][j], rg[al][j], g2[j]);
                s1[j] += rs[al][j]; s2[j] = fmaf(rs[al][j], rs[al][j], s2[j]);
            }
        }
        // Prefetch add-row of iteration i+3 (row y+6) into its slot.
        // (Slot (i+9)%RING was sub-read above in this same iteration.)
        if (i + 3 < SUB_H) {
            const int pl = (i + 9) % RING;
            rg[pl] = ld(Gp, y + 6);
            rs[pl] = ld(Sp, y + 6);
        }

        // Horizontal 7-sums via DPP wave shifts (pure VALU).
        float hg1[4], hg2[4], hs1[4], hs2[4];
        auto hsum = [&](const float* c, float* o) {
            const float t1 = c[0] + c[1], t2 = c[2] + c[3];
            const float S4 = t1 + t2;
            const float sfx3 = c[1] + t2;     // c1+c2+c3
            const float pfx3 = t1 + c[2];     // c0+c1+c2
            const float S1m = dpp_up1(c[3]);
            const float S2m = dpp_up1(t2);
            const float S3m = dpp_up1(sfx3);
            const float P1p = dpp_dn1(c[0]);
            const float P2p = dpp_dn1(t1);
            const float P3p = dpp_dn1(pfx3);
            o[0] = S3m + S4;
            o[1] = S2m + S4 + P1p;
            o[2] = S1m + S4 + P2p;
            o[3] = S4 + P3p;
        };
        hsum(g1, hg1); hsum(g2, hg2); hsum(s1, hs1); hsum(s2, hs2);

        const float cnty = (float)(min(y + HALO, H - 1) - max(y - HALO, 0) + 1);

        f32x4 av, bv;
#pragma unroll
        for (int j = 0; j < 4; ++j) {
            const float cnt  = cntx[j] * cnty;
            const float inv  = rcp_fast(cnt);
            const float invm = rcp_fast(cnt - 1.0f);
            const float mg = hg1[j] * inv;
            const float ms = hs1[j] * inv;
            const float varg = (hg2[j] - hg1[j] * mg) * invm;
            const float vars = (hs2[j] - hs1[j] * ms) * invm;
            const float stdg = __builtin_amdgcn_sqrtf(fmaxf(varg, 0.0f));
            const float stds = __builtin_amdgcn_sqrtf(fmaxf(vars, 0.0f));
            const float alpha = stdg * rcp_fast(stds + EPS);
            av[j] = alpha;
            bv[j] = mg - alpha * ms;
        }

        if (wout) {
            const size_t base = (size_t)ch * plane + (size_t)y * W + col0;
            __builtin_nontemporal_store(av, reinterpret_cast<f32x4*>(out + base));
            __builtin_nontemporal_store(bv, reinterpret_cast<f32x4*>(out + 3 * plane + base));
        }
    }
}

extern "C" void kernel_launch(void* const* d_in, const int* in_sizes, int n_in,
                              void* d_out, int out_size, void* d_ws, size_t ws_size,
                              hipStream_t stream) {
    (void)n_in; (void)d_ws; (void)ws_size; (void)in_sizes; (void)out_size;
    const float* guidance = (const float*)d_in[0];
    const float* source   = (const float*)d_in[1];
    float* out = (float*)d_out;

    const int H = 2048, W = 3072;

    dim3 block(64, WAVES_Y, 1);
    dim3 grid(NSTRIPS, NYT, NCH);                      // 13 x 32 x 3 = 1248
    ProgressiveTransfer_kernel<<<grid, block, 0, stream>>>(guidance, source, out, H, W);
}